// Round 12
// baseline (505.145 us; speedup 1.0000x reference)
//
#include <hip/hip_runtime.h>

#define T_SEQ 512
#define HID   50
#define NB    4           // batch rows per block (MFMA N=16, cols 0-3 valid)
#define BLK   512         // 8 waves: 0-3 layer0, 4-7 layer1 (1-step skew)

typedef float v4f  __attribute__((ext_vector_type(4)));
typedef _Float16 f16;
typedef f16  f16x8 __attribute__((ext_vector_type(8)));

// R11 = R10 layer-pipelined structure (1 barrier/superstep, dbuf hA/hB frag
// tiles, bias@k63 / x@k62 in MFMA K-padding, Montgomery epilogue) with
// NB 8->4, BLK 1024->512, grid 512 => TWO co-resident blocks per CU.
// R10 evidence: ~700cyc/step stall at 1 block/CU (all waves drain at the
// same barrier). Two blocks share no barrier -> drain overlap. Per-CU work:
// VALU/epilogue unchanged, MFMA doubles (~750cyc pipe < ~930 VALU ceiling).
// Epilogue packs FOUR Mtiles per UPDW2: 2-level shfl tree (xor8, xor4):
//   lane n16 = 4*mi + nn  (mi = Mtile idx, nn = batch 0-3).
// VGPR: worst wave 16 f16x8 + temps ~110; amdgpu_waves_per_eu(4,4) pins the
// budget at 128 exactly (R4 lesson: min-only (4) let allocator shrink to 64).
// B-frag tiles (f16, 8 k-tiles of 32): 0,1=hA buf0 (x@k62,1@k63); 2,3=hA buf1;
// 4,5=hB buf0; 6,7=hB buf1. Superstep s: rb=(s+1)&1, wb=s&1 (hazards: R9 proof).
// MFMA 16x16x32_f16: A[m=lane&15][k=(lane>>4)*8+j]; B[k=(lane>>4)*8+j][n=lane&15];
// C reg r = C[row=(lane>>4)*4+r][col=lane&15].  M layout: m=4u+g (gate-interleaved).

__device__ __forceinline__ f16x8 ldA0(const float* __restrict__ Whh0,
                                      const float* __restrict__ Wih0,
                                      const float* __restrict__ bih0,
                                      const float* __restrict__ bhh0,
                                      int m, int kb) {
    const int u = m >> 2, g = m & 3;
    f16x8 v;
    #pragma unroll
    for (int j = 0; j < 8; ++j) {
        const int k = kb + j;
        float f = 0.f;
        if (u < HID) {
            const int rho = g * HID + u;
            if (k < HID)      f = Whh0[rho * HID + k];
            else if (k == 62) f = Wih0[rho];
            else if (k == 63) f = bih0[rho] + bhh0[rho];
        }
        v[j] = (f16)f;
    }
    return v;
}

__device__ __forceinline__ f16x8 ldA1a(const float* __restrict__ Wih1,
                                       const float* __restrict__ bih1,
                                       const float* __restrict__ bhh1,
                                       int m, int kb) {
    const int u = m >> 2, g = m & 3;
    f16x8 v;
    #pragma unroll
    for (int j = 0; j < 8; ++j) {
        const int k = kb + j;
        float f = 0.f;
        if (u < HID) {
            const int rho = g * HID + u;
            if (k < HID)      f = Wih1[rho * HID + k];
            else if (k == 63) f = bih1[rho] + bhh1[rho];
        }
        v[j] = (f16)f;
    }
    return v;
}

__device__ __forceinline__ f16x8 ldA1b(const float* __restrict__ Whh1,
                                       int m, int kb) {
    const int u = m >> 2, g = m & 3;
    f16x8 v;
    #pragma unroll
    for (int j = 0; j < 8; ++j) {
        const int k = kb + j;
        float f = 0.f;
        if (u < HID && k < HID) f = Whh1[(g * HID + u) * HID + k];
        v[j] = (f16)f;
    }
    return v;
}

__global__ __launch_bounds__(BLK)
__attribute__((amdgpu_waves_per_eu(4, 4)))
void lstm2_mfma(const float* __restrict__ x,
                const float* __restrict__ Wih0,
                const float* __restrict__ Whh0,
                const float* __restrict__ bih0,
                const float* __restrict__ bhh0,
                const float* __restrict__ Wih1,
                const float* __restrict__ Whh1,
                const float* __restrict__ bih1,
                const float* __restrict__ bhh1,
                const float* __restrict__ Wfc,
                const float* __restrict__ bfc,
                float* __restrict__ out)
{
    __shared__ __align__(16) f16 BPH [8 * 64 * 8];   // 8,192 B: B frags (dbuf hA/hB)
    __shared__ f16   xs16[NB][T_SEQ];                // 4,096 B: staged x (f16)
    __shared__ float hfin[HID][NB];                  //   800 B: final hB fp32

    const int tid  = threadIdx.x;
    const int w    = tid >> 6;
    const int lane = tid & 63;
    const int n16  = lane & 15;
    const int quad = lane >> 4;
    const int bb0  = blockIdx.x * NB;
    const bool isL1 = (w >= 4);
    const int wl   = w & 3;                          // index within layer group
    const int nmt  = (wl == 0) ? 4 : 3;              // Mtiles: {4,3,3,3}
    const int mtb  = (wl == 0) ? 0 : (3 * wl + 1);   // first Mtile: 0,4,7,10

    const float* xg = x + (long)bb0 * T_SEQ;

    // ---- one-time: zero B frags; stage x -> f16 LDS ----
    for (int i = tid; i < 8 * 64 * 8; i += BLK) BPH[i] = (f16)0.f;
    for (int i = tid; i < NB * T_SEQ; i += BLK) {
        const int n = i >> 9, tt = i & (T_SEQ - 1);
        xs16[n][tt] = (f16)xg[n * T_SEQ + tt];
    }

    // ---- one-time: this wave's layer weights into named SSA registers ----
    f16x8 u0_0 = {}, u1_0 = {}, u2_0 = {}, u3_0 = {};
    f16x8 u0_1 = {}, u1_1 = {}, u2_1 = {}, u3_1 = {};
    f16x8 u0_2 = {}, u1_2 = {}, u2_2 = {}, u3_2 = {};
    f16x8 u0_3 = {}, u1_3 = {}, u2_3 = {}, u3_3 = {};
#define LDSET(I) if ((I) < nmt) { \
    const int m = (mtb + (I)) * 16 + n16, kb0 = quad * 8, kb1 = 32 + quad * 8; \
    if (!isL1) { \
        u0_##I = ldA0(Whh0, Wih0, bih0, bhh0, m, kb0); \
        u1_##I = ldA0(Whh0, Wih0, bih0, bhh0, m, kb1); \
    } else { \
        u0_##I = ldA1a(Wih1, bih1, bhh1, m, kb0); \
        u1_##I = ldA1a(Wih1, bih1, bhh1, m, kb1); \
        u2_##I = ldA1b(Whh1, m, kb0); \
        u3_##I = ldA1b(Whh1, m, kb1); \
    } }
    LDSET(0) LDSET(1) LDSET(2) LDSET(3)

    __syncthreads();
    // "1.0" bias lanes (k=63) in both hA bufs; x(0) into hA buf1 (read at s=0)
    if (tid < NB) {
        BPH[(1 * 64 + 48 + tid) * 8 + 7] = (f16)1.f;
        BPH[(3 * 64 + 48 + tid) * 8 + 7] = (f16)1.f;
        BPH[(3 * 64 + 48 + tid) * 8 + 6] = xs16[tid][0];
    }
    __syncthreads();

    // per-lane epilogue slot: Mtile mi = n16>>2, batch nn = n16&3
    const int mi = n16 >> 2;
    const int nn = n16 & 3;
    const int u_ = (mtb + mi) * 4 + quad;
    const bool valid = (mi < nmt) && (u_ < HID);
    float cs = 0.f;
    const f16x8* BPF = (const f16x8*)BPH;

#define MFMA16(A, B, C) __builtin_amdgcn_mfma_f32_16x16x32_f16((A), (B), (C), 0, 0, 0)

    // pack C0..C3 (4 Mtiles, valid cols 0-3 each) into CC: lane 4*mi+nn
#define PACKC(F) { \
    const float a2 = __shfl_xor(C2.F, 8); \
    const float a3 = __shfl_xor(C3.F, 8); \
    const float t02 = (n16 < 8) ? C0.F : a2; \
    const float t13 = (n16 < 8) ? C1.F : a3; \
    const float t13s = __shfl_xor(t13, 4); \
    CC.F = ((n16 & 4) == 0) ? t02 : t13s; }

    // packed LSTM epilogue: CC = (i,f,g,o) preacts of (unit u_, batch nn).
    // Montgomery batch-inversion: 1 rcp for the 4 gate denominators.
#define UPDW2(C, TBASE, DOFIN) { \
    const float e1 = __expf(-C.x); \
    const float e2 = __expf(-C.y); \
    const float e3 = __expf(-2.f * C.z); \
    const float e4 = __expf(-C.w); \
    const float d1 = 1.f + e1, d2 = 1.f + e2, d3 = 1.f + e3, d4 = 1.f + e4; \
    const float p2 = d1 * d2, p3 = p2 * d3, p4 = p3 * d4; \
    const float i4 = __builtin_amdgcn_rcpf(p4); \
    const float go = i4 * p3;                 /* 1/d4 */ \
    const float i3 = i4 * d4; \
    const float r3 = i3 * p2;                 /* 1/d3 */ \
    const float i2 = i3 * d3; \
    const float gf = i2 * d1;                 /* 1/d2 */ \
    const float gi = i2 * d2;                 /* 1/d1 */ \
    const float gg = fmaf(2.f, r3, -1.f); \
    cs = fmaf(gf, cs, gi * gg); \
    const float th = fmaf(2.f, __builtin_amdgcn_rcpf(1.f + __expf(-2.f * cs)), -1.f); \
    const float hh = go * th; \
    if (valid) { \
        BPH[(((TBASE) + (u_ >> 5)) * 64 + ((u_ & 31) >> 3) * 16 + nn) * 8 + (u_ & 7)] = (f16)hh; \
        DOFIN \
    } }

    #pragma clang loop unroll(disable)
    for (int s = 0; s <= T_SEQ; ++s) {
        const int rb = (s + 1) & 1, wb = s & 1;
        if (!isL1) {
            // ---- layer0 @ s: hA(s) = upd([Whh0|wx|b0] @ [hA(s-1);x(s);1]) ----
            if (s < T_SEQ) {
                const f16x8 B0 = BPF[(2 * rb + 0) * 64 + lane];
                const f16x8 B1 = BPF[(2 * rb + 1) * 64 + lane];
                v4f C0 = {0.f,0.f,0.f,0.f}, C1 = {0.f,0.f,0.f,0.f};
                v4f C2 = {0.f,0.f,0.f,0.f}, C3 = {0.f,0.f,0.f,0.f};
                C0 = MFMA16(u0_0, B0, C0); C0 = MFMA16(u1_0, B1, C0);
                C1 = MFMA16(u0_1, B0, C1); C1 = MFMA16(u1_1, B1, C1);
                C2 = MFMA16(u0_2, B0, C2); C2 = MFMA16(u1_2, B1, C2);
                if (nmt == 4) {
                    C3 = MFMA16(u0_3, B0, C3); C3 = MFMA16(u1_3, B1, C3);
                }
                v4f CC;
                PACKC(x) PACKC(y) PACKC(z) PACKC(w)
                UPDW2(CC, 2 * wb, {})
                // x(s+1) -> hA(s)'s buf @k62; read at s+1 (1 barrier away)
                if (w == 0 && lane < NB && s + 1 < T_SEQ)
                    BPH[((2 * wb + 1) * 64 + 48 + lane) * 8 + 6] = xs16[lane][s + 1];
            }
        } else {
            // ---- layer1 @ s: hB(s-1) = upd([Wih1|b1]@[hA(s-1);1] + Whh1@hB(s-2)) ----
            if (s >= 1) {
                const f16x8 B0 = BPF[(2 * rb + 0) * 64 + lane];        // hA(s-1)
                const f16x8 B1 = BPF[(2 * rb + 1) * 64 + lane];
                const f16x8 B2 = BPF[(4 + 2 * wb + 0) * 64 + lane];    // hB(s-2)
                const f16x8 B3 = BPF[(4 + 2 * wb + 1) * 64 + lane];
                v4f C0 = {0.f,0.f,0.f,0.f}, C1 = {0.f,0.f,0.f,0.f};
                v4f C2 = {0.f,0.f,0.f,0.f}, C3 = {0.f,0.f,0.f,0.f};
                C0 = MFMA16(u0_0, B0, C0); C0 = MFMA16(u1_0, B1, C0);
                C0 = MFMA16(u2_0, B2, C0); C0 = MFMA16(u3_0, B3, C0);
                C1 = MFMA16(u0_1, B0, C1); C1 = MFMA16(u1_1, B1, C1);
                C1 = MFMA16(u2_1, B2, C1); C1 = MFMA16(u3_1, B3, C1);
                C2 = MFMA16(u0_2, B0, C2); C2 = MFMA16(u1_2, B1, C2);
                C2 = MFMA16(u2_2, B2, C2); C2 = MFMA16(u3_2, B3, C2);
                if (nmt == 4) {
                    C3 = MFMA16(u0_3, B0, C3); C3 = MFMA16(u1_3, B1, C3);
                    C3 = MFMA16(u2_3, B2, C3); C3 = MFMA16(u3_3, B3, C3);
                }
                v4f CC;
                PACKC(x) PACKC(y) PACKC(z) PACKC(w)
                UPDW2(CC, 4 + 2 * rb,
                      { if (s == T_SEQ) hfin[u_][nn] = hh; })
            }
        }
        __syncthreads();   // the ONE barrier: publishes hA(s), hB(s-1), x(s+1)
    }

    // ---- classifier: out[n][c] = hB[n] . Wfc[c] + bfc[c] ----
    if (tid < NB * 2) {
        const int b = tid >> 1, c = tid & 1;
        float acc = bfc[c];
        #pragma unroll
        for (int u = 0; u < HID; ++u)
            acc = fmaf(Wfc[c * HID + u], hfin[u][b], acc);
        out[(bb0 + b) * 2 + c] = acc;
    }
}

extern "C" void kernel_launch(void* const* d_in, const int* in_sizes, int n_in,
                              void* d_out, int out_size, void* d_ws, size_t ws_size,
                              hipStream_t stream) {
    const float* x    = (const float*)d_in[0];
    const float* Wih0 = (const float*)d_in[1];
    const float* Whh0 = (const float*)d_in[2];
    const float* bih0 = (const float*)d_in[3];
    const float* bhh0 = (const float*)d_in[4];
    const float* Wih1 = (const float*)d_in[5];
    const float* Whh1 = (const float*)d_in[6];
    const float* bih1 = (const float*)d_in[7];
    const float* bhh1 = (const float*)d_in[8];
    const float* Wfc  = (const float*)d_in[9];
    const float* bfc  = (const float*)d_in[10];
    float* out = (float*)d_out;

    const int B = in_sizes[0] / T_SEQ;   // D == 1
    const int grid = B / NB;             // 2048/4 = 512 blocks -> 2 blocks/CU

    hipLaunchKernelGGL(lstm2_mfma, dim3(grid), dim3(BLK), 0, stream,
                       x, Wih0, Whh0, bih0, bhh0, Wih1, Whh1, bih1, bhh1,
                       Wfc, bfc, out);
}